// Round 1
// 1149.147 us; speedup vs baseline: 1.0359x; 1.0359x over previous
//
#include <hip/hip_runtime.h>
#include <stdint.h>
#include <stddef.h>

#define Bn    16
#define Nn    10000
#define En    320000
#define CIN   32
#define COUTn 64
#define CCn   96
#define WROWU 768           // uints per full node row (16 batches * 96ch / 2)
#define RHU   512           // uints per rh-only node row (16 * 64 / 2)
#define MROWS 160000        // Nn * Bn

typedef __attribute__((ext_vector_type(8))) short short8;   // 8 bf16 = 4 VGPRs
typedef __attribute__((ext_vector_type(4))) float f32x4;

// ---------------- bf16 helpers ----------------
__device__ __forceinline__ float bflo(unsigned int p) { return __uint_as_float(p << 16); }
__device__ __forceinline__ float bfhi(unsigned int p) { return __uint_as_float(p & 0xffff0000u); }
__device__ __forceinline__ float bf2f(unsigned short u) { return __uint_as_float(((unsigned int)u) << 16); }
__device__ __forceinline__ unsigned int f2bfbits(float f) {
  unsigned int x = __float_as_uint(f);
  return (x + 0x7fffu + ((x >> 16) & 1u)) >> 16;
}
__device__ __forceinline__ unsigned int pack2(float lo, float hi) {
  return f2bfbits(lo) | (f2bfbits(hi) << 16);
}

// ---------------- edge_index dtype detection ----------------
__global__ void detect_idx(const int* __restrict__ idx, int* __restrict__ flag) {
  if (threadIdx.x == 0 && blockIdx.x == 0) {
    int is64 = 1;
    for (int i = 1; i < 128; i += 2) {
      if (idx[i] != 0) { is64 = 0; break; }
    }
    flag[0] = is64;
  }
}

__device__ __forceinline__ int gidx(const int* __restrict__ p, int i, int is64) {
  return is64 ? p[2 * (long long)i] : p[i];
}

// ---------------- degree + CSR row counts ----------------
__global__ void deg_cnt_kernel(const int* __restrict__ idx, const float* __restrict__ w,
                               float* __restrict__ deg_f, float* __restrict__ deg_b,
                               int* __restrict__ cnt_f, int* __restrict__ cnt_b,
                               const int* __restrict__ flag) {
  int e = blockIdx.x * 256 + threadIdx.x;
  int is64 = flag[0];
  if (e < En) {
    int s = gidx(idx, e, is64);
    int d = gidx(idx, En + e, is64);
    float we = w[e];
    atomicAdd(&deg_f[s], we);
    atomicAdd(&deg_b[d], we);
    atomicAdd(&cnt_f[d], 1);
    atomicAdd(&cnt_b[s], 1);
  }
}

// ---------------- exclusive scan ----------------
__global__ void exscan_two(const int* __restrict__ cnt_f, const int* __restrict__ cnt_b,
                           int* __restrict__ rp_f, int* __restrict__ rp_b,
                           int* __restrict__ cur_f, int* __restrict__ cur_b, int n) {
  const int* cnt = (blockIdx.x == 0) ? cnt_f : cnt_b;
  int* rp  = (blockIdx.x == 0) ? rp_f  : rp_b;
  int* cur = (blockIdx.x == 0) ? cur_f : cur_b;
  __shared__ int sh[256];
  int t = threadIdx.x;
  int running = 0;
  for (int base = 0; base < n; base += 256) {
    int v = (base + t < n) ? cnt[base + t] : 0;
    sh[t] = v;
    __syncthreads();
    for (int off = 1; off < 256; off <<= 1) {
      int x = (t >= off) ? sh[t - off] : 0;
      __syncthreads();
      sh[t] += x;
      __syncthreads();
    }
    int excl = sh[t] - v;
    if (base + t < n) { rp[base + t] = running + excl; cur[base + t] = running + excl; }
    int total = sh[255];
    __syncthreads();
    running += total;
  }
  if (t == 0) rp[n] = running;
}

// ---------------- CSR fill: packed (col, w) uint2 ----------------
__global__ void fill_csr(const int* __restrict__ idx, const float* __restrict__ w,
                         const float* __restrict__ deg_f, const float* __restrict__ deg_b,
                         int* __restrict__ cur_f, int* __restrict__ cur_b,
                         uint2* __restrict__ cwf, uint2* __restrict__ cwb,
                         const int* __restrict__ flag) {
  int e = blockIdx.x * 256 + threadIdx.x;
  int is64 = flag[0];
  if (e < En) {
    int s = gidx(idx, e, is64);
    int d = gidx(idx, En + e, is64);
    float we = w[e];
    int pf = atomicAdd(&cur_f[d], 1);
    cwf[pf] = make_uint2((unsigned int)s, __float_as_uint(we / deg_f[s]));
    int pb = atomicAdd(&cur_b[s], 1);
    cwb[pb] = make_uint2((unsigned int)d, __float_as_uint(we / deg_b[d]));
  }
}

// ---------------- weight prep: transposed bf16, W0 folded (W0-W3-W4) ----------------
__global__ void build_wt(const float* __restrict__ ru_p, const float* __restrict__ c_p,
                         unsigned short* __restrict__ Wt1, unsigned short* __restrict__ Wt2) {
  int i = blockIdx.x * 256 + threadIdx.x;
  if (i < 128 * 480) {
    int n = i / 480, k = i % 480;
    int t = k / 96, kk = k % 96;
    float v;
    if (t == 0) v = ru_p[(kk * 5 + 0) * 128 + n] - ru_p[(kk * 5 + 3) * 128 + n] - ru_p[(kk * 5 + 4) * 128 + n];
    else        v = ru_p[(kk * 5 + t) * 128 + n];
    Wt1[i] = (unsigned short)f2bfbits(v);
  }
  if (i < 64 * 480) {
    int n = i / 480, k = i % 480;
    int t = k / 96, kk = k % 96;
    float v;
    if (t == 0) v = c_p[(kk * 5 + 0) * 64 + n] - c_p[(kk * 5 + 3) * 64 + n] - c_p[(kk * 5 + 4) * 64 + n];
    else        v = c_p[(kk * 5 + t) * 64 + n];
    Wt2[i] = (unsigned short)f2bfbits(v);
  }
}

// ---------------- X0 builder ----------------
__global__ void build_x0_ru(const float* __restrict__ x, const float* __restrict__ h,
                            unsigned int* __restrict__ X0) {
  long long p = (long long)blockIdx.x * 256 + threadIdx.x;
  int node = (int)(p / WROWU);
  int rem = (int)(p % WROWU);
  int b = rem / 48;
  int ci = (rem % 48) * 2;
  float lo, hi;
  if (ci < CIN) {
    const float* s = x + ((size_t)b * Nn + node) * CIN + ci;
    lo = s[0]; hi = s[1];
  } else {
    const float* s = h + ((size_t)b * Nn + node) * COUTn + (ci - CIN);
    lo = s[0]; hi = s[1];
  }
  X0[p] = pack2(lo, hi);
}

// ---------------- XCD-sliced propagation ----------------
// Node rows of RU2 uint2 are split into 8 channel slices of SL2 uint2.
// slice = blockIdx & 7  -> with round-robin WG dispatch, each XCD only
// gathers its own Nn*SL2*8-byte slice (<= 3.84 MB), fitting its 4 MiB L2.
// One wave per row: row bounds are wave-uniform (readfirstlane -> s_loads
// for the packed (col,w) edges), no LDS, no __syncthreads.
template<int RU2, int SL2>
__device__ __forceinline__ void prop_row(const uint2* __restrict__ in,
                                         const uint2* __restrict__ cw,
                                         int jb, int je, int u2, bool act,
                                         float& a0, float& a1, float& a2, float& a3) {
  int j = jb;
  for (; j + 4 <= je; j += 4) {
    uint2 e0 = cw[j + 0];
    uint2 e1 = cw[j + 1];
    uint2 e2 = cw[j + 2];
    uint2 e3 = cw[j + 3];
    if (act) {
      uint2 p0 = in[e0.x * RU2 + u2];
      uint2 p1 = in[e1.x * RU2 + u2];
      uint2 p2 = in[e2.x * RU2 + u2];
      uint2 p3 = in[e3.x * RU2 + u2];
      float w0 = __uint_as_float(e0.y), w1 = __uint_as_float(e1.y);
      float w2 = __uint_as_float(e2.y), w3 = __uint_as_float(e3.y);
      a0 += w0 * bflo(p0.x); a1 += w0 * bfhi(p0.x); a2 += w0 * bflo(p0.y); a3 += w0 * bfhi(p0.y);
      a0 += w1 * bflo(p1.x); a1 += w1 * bfhi(p1.x); a2 += w1 * bflo(p1.y); a3 += w1 * bfhi(p1.y);
      a0 += w2 * bflo(p2.x); a1 += w2 * bfhi(p2.x); a2 += w2 * bflo(p2.y); a3 += w2 * bfhi(p2.y);
      a0 += w3 * bflo(p3.x); a1 += w3 * bfhi(p3.x); a2 += w3 * bflo(p3.y); a3 += w3 * bfhi(p3.y);
    }
  }
  for (; j < je; ++j) {
    uint2 e0 = cw[j];
    if (act) {
      uint2 p0 = in[e0.x * RU2 + u2];
      float w0 = __uint_as_float(e0.y);
      a0 += w0 * bflo(p0.x); a1 += w0 * bfhi(p0.x); a2 += w0 * bflo(p0.y); a3 += w0 * bfhi(p0.y);
    }
  }
}

template<int RU2, int SL2>
__launch_bounds__(256)
__global__ void prop_dual_s(const uint2* __restrict__ in,
                            uint2* __restrict__ outF, uint2* __restrict__ outB,
                            const int* __restrict__ rp_f, const uint2* __restrict__ cwf,
                            const int* __restrict__ rp_b, const uint2* __restrict__ cwb) {
  int tid = threadIdx.x;
  int lane = tid & 63;
  int wave = tid >> 6;
  int slice = blockIdx.x & 7;
  int row = ((blockIdx.x >> 3) << 2) + wave;
  int u2 = slice * SL2 + lane;
  bool act = lane < SL2;
  {
    float a0 = 0.f, a1 = 0.f, a2 = 0.f, a3 = 0.f;
    int jb = __builtin_amdgcn_readfirstlane(rp_f[row]);
    int je = __builtin_amdgcn_readfirstlane(rp_f[row + 1]);
    prop_row<RU2, SL2>(in, cwf, jb, je, u2, act, a0, a1, a2, a3);
    if (act) {
      uint2 o; o.x = pack2(a0, a1); o.y = pack2(a2, a3);
      outF[(size_t)row * RU2 + u2] = o;
    }
  }
  {
    float a0 = 0.f, a1 = 0.f, a2 = 0.f, a3 = 0.f;
    int jb = __builtin_amdgcn_readfirstlane(rp_b[row]);
    int je = __builtin_amdgcn_readfirstlane(rp_b[row + 1]);
    prop_row<RU2, SL2>(in, cwb, jb, je, u2, act, a0, a1, a2, a3);
    if (act) {
      uint2 o; o.x = pack2(a0, a1); o.y = pack2(a2, a3);
      outB[(size_t)row * RU2 + u2] = o;
    }
  }
}

template<int RU2, int SL2>
__launch_bounds__(256)
__global__ void prop_ck_s(const uint2* __restrict__ in, uint2* __restrict__ out,
                          const int* __restrict__ rp, const uint2* __restrict__ cw,
                          float alpha) {
  int tid = threadIdx.x;
  int lane = tid & 63;
  int wave = tid >> 6;
  int slice = blockIdx.x & 7;
  int row = ((blockIdx.x >> 3) << 2) + wave;
  int u2 = slice * SL2 + lane;
  bool act = lane < SL2;
  float a0 = 0.f, a1 = 0.f, a2 = 0.f, a3 = 0.f;
  int jb = __builtin_amdgcn_readfirstlane(rp[row]);
  int je = __builtin_amdgcn_readfirstlane(rp[row + 1]);
  prop_row<RU2, SL2>(in, cw, jb, je, u2, act, a0, a1, a2, a3);
  if (act) {
    uint2 o; o.x = pack2(alpha * a0, alpha * a1); o.y = pack2(alpha * a2, alpha * a3);
    out[(size_t)row * RU2 + u2] = o;
  }
}

// ---------------- MFMA multi-term GEMM ----------------
// C[128 x NT] per block; 4 waves, each 32 x NT. K = nterms*96.
// Weight columns for loop term t are taken at (t0 + t)*96.
// MFMA layouts (verified): A[m=lane&15][k=quad*8+j]; B[k=quad*8+j][n=lane&15];
//                          C/D col=lane&15, row=quad*4+reg.
// MODE 0: conv1 epilogue: v=sigmoid(bias+acc); col<64 -> rh0=v*h (bf16); else U=v (bf16)
// MODE 1: outp = bias + acc (f32, batch-major)
// MODE 2: cp = outp + acc; c=tanh(tanh(cp)); u from U_in; outp = u*h + (1-u)*c
struct Msrc {
  const uint4* xs[5];
  const uint4* rh[5];
};

template<int NT, int MODE>
__launch_bounds__(256)
__global__ void gemm_mfma(Msrc g, int nterms, int t0,
                          const unsigned short* __restrict__ Wt,
                          const float* __restrict__ bias,
                          float* __restrict__ outp,
                          unsigned short* __restrict__ rh0_s,
                          unsigned short* __restrict__ U_out,
                          const unsigned short* __restrict__ U_in,
                          const float* __restrict__ hglob) {
  constexpr int NJ = NT / 16;
  __shared__ __align__(16) unsigned short As[128][104];   // 13 x 16B per row (odd -> conflict-free)
  __shared__ __align__(16) unsigned short Bs[NT][104];

  int m0 = blockIdx.x * 128;
  int tid = threadIdx.x;
  int wave = tid >> 6;
  int lane = tid & 63;
  int quad = lane >> 4;
  int lm = lane & 15;
  int wm = wave * 32;
  int nodeBase = m0 >> 4;

  f32x4 acc[2][NJ];
  #pragma unroll
  for (int i = 0; i < 2; ++i)
    #pragma unroll
    for (int j = 0; j < NJ; ++j) acc[i][j] = (f32x4){0.f, 0.f, 0.f, 0.f};

  for (int t = 0; t < nterms; ++t) {
    const uint4* xs4 = g.xs[t];
    const uint4* rh4 = g.rh[t];
    if (rh4 == nullptr) {
      const uint4* src = xs4 + (size_t)m0 * 12;
      #pragma unroll
      for (int it = 0; it < 6; ++it) {
        int q = tid + it * 256;
        uint4 v = src[q];
        int row = q / 12, slot = q % 12;
        *(uint4*)&As[row][slot * 8] = v;
      }
    } else {
      #pragma unroll
      for (int it = 0; it < 6; ++it) {
        int q = tid + it * 256;
        int row = q / 12, slot = q % 12;
        int node = nodeBase + (row >> 4);
        int b = row & 15;
        uint4 v; int ci0;
        if (slot < 4) { v = xs4[(size_t)node * 192 + b * 12 + slot]; ci0 = slot * 8; }
        else          { v = rh4[(size_t)node * 128 + b * 8 + (slot - 4)]; ci0 = 32 + (slot - 4) * 8; }
        *(uint4*)&As[row][ci0] = v;
      }
    }
    for (int q = tid; q < NT * 12; q += 256) {
      int n = q / 12, slot = q % 12;
      uint4 v = *(const uint4*)(Wt + (size_t)n * 480 + (t0 + t) * 96 + slot * 8);
      *(uint4*)&Bs[n][slot * 8] = v;
    }
    __syncthreads();

    #pragma unroll
    for (int k32 = 0; k32 < 3; ++k32) {
      int kb = k32 * 32 + quad * 8;
      short8 a0 = *(const short8*)&As[wm + lm][kb];
      short8 a1 = *(const short8*)&As[wm + 16 + lm][kb];
      #pragma unroll
      for (int j = 0; j < NJ; ++j) {
        short8 bf = *(const short8*)&Bs[j * 16 + lm][kb];
        acc[0][j] = __builtin_amdgcn_mfma_f32_16x16x32_bf16(a0, bf, acc[0][j], 0, 0, 0);
        acc[1][j] = __builtin_amdgcn_mfma_f32_16x16x32_bf16(a1, bf, acc[1][j], 0, 0, 0);
      }
    }
    __syncthreads();
  }

  #pragma unroll
  for (int i = 0; i < 2; ++i) {
    #pragma unroll
    for (int j = 0; j < NJ; ++j) {
      int col = j * 16 + lm;
      #pragma unroll
      for (int r = 0; r < 4; ++r) {
        int row = m0 + wm + i * 16 + quad * 4 + r;
        int node = row >> 4, b = row & 15;
        float v = acc[i][j][r];
        if (MODE == 0) {
          float s = 1.f / (1.f + expf(-(bias[col] + v)));
          if (col < COUTn) {
            float hv = hglob[((size_t)b * Nn + node) * COUTn + col];
            rh0_s[(size_t)row * 64 + col] = (unsigned short)f2bfbits(s * hv);
          } else {
            U_out[(size_t)row * 64 + (col - COUTn)] = (unsigned short)f2bfbits(s);
          }
        } else if (MODE == 1) {
          outp[((size_t)b * Nn + node) * COUTn + col] = bias[col] + v;
        } else {
          size_t oa = ((size_t)b * Nn + node) * COUTn + col;
          float cp = outp[oa] + v;
          float c = tanhf(tanhf(cp));
          float u = bf2f(U_in[(size_t)row * 64 + col]);
          outp[oa] = u * hglob[oa] + (1.f - u) * c;
        }
      }
    }
  }
}

// ---------------- host ----------------
extern "C" void kernel_launch(void* const* d_in, const int* in_sizes, int n_in,
                              void* d_out, int out_size, void* d_ws, size_t ws_size,
                              hipStream_t stream) {
  const float* x   = (const float*)d_in[0];
  const float* h   = (const float*)d_in[1];
  const int*   idx = (const int*)d_in[2];
  const float* ew  = (const float*)d_in[3];
  const float* ru_param = (const float*)d_in[4];
  const float* ru_bias  = (const float*)d_in[5];
  const float* c_param  = (const float*)d_in[6];
  const float* c_bias   = (const float*)d_in[7];
  float* outp = (float*)d_out;
  (void)in_sizes; (void)n_in; (void)out_size; (void)ws_size;

  char* ws = (char*)d_ws;
  size_t off = 0;
  auto alloc = [&](size_t bytes) -> char* {
    char* p = ws + off;
    off += (bytes + 255) & ~(size_t)255;
    return p;
  };

  float* deg_f = (float*)alloc(40960);
  float* deg_b = (float*)alloc(40960);
  int*   cnt_f = (int*)alloc(40960);
  int*   cnt_b = (int*)alloc(40960);
  int*   rp_f  = (int*)alloc((Nn + 1) * sizeof(int));
  int*   rp_b  = (int*)alloc((Nn + 1) * sizeof(int));
  int*   cur_f = (int*)alloc(Nn * sizeof(int));
  int*   cur_b = (int*)alloc(Nn * sizeof(int));
  int*   flag  = (int*)alloc(256);
  uint2* cwf   = (uint2*)alloc((size_t)En * 8);
  uint2* cwb   = (uint2*)alloc((size_t)En * 8);
  unsigned short* Wt1 = (unsigned short*)alloc(128 * 480 * 2);
  unsigned short* Wt2 = (unsigned short*)alloc(64 * 480 * 2);

  unsigned int* A0   = (unsigned int*)alloc((size_t)Nn * WROWU * 4);
  unsigned int* T1f  = (unsigned int*)alloc((size_t)Nn * WROWU * 4);
  unsigned int* T1b  = (unsigned int*)alloc((size_t)Nn * WROWU * 4);
  unsigned int* T2f  = (unsigned int*)alloc((size_t)Nn * WROWU * 4);
  unsigned int* T2b  = (unsigned int*)alloc((size_t)Nn * WROWU * 4);
  unsigned int* rh0  = (unsigned int*)alloc((size_t)Nn * RHU * 4);
  unsigned int* rh1f = (unsigned int*)alloc((size_t)Nn * RHU * 4);
  unsigned int* rh1b = (unsigned int*)alloc((size_t)Nn * RHU * 4);
  unsigned int* Ubuf = (unsigned int*)alloc((size_t)Nn * RHU * 4);
  // ~241 MB total

  hipMemsetAsync(ws, 0, 4 * 40960, stream);
  detect_idx<<<1, 64, 0, stream>>>(idx, flag);
  deg_cnt_kernel<<<En / 256, 256, 0, stream>>>(idx, ew, deg_f, deg_b, cnt_f, cnt_b, flag);
  exscan_two<<<2, 256, 0, stream>>>(cnt_f, cnt_b, rp_f, rp_b, cur_f, cur_b, Nn);
  fill_csr<<<En / 256, 256, 0, stream>>>(idx, ew, deg_f, deg_b, cur_f, cur_b,
                                         cwf, cwb, flag);
  build_wt<<<240, 256, 0, stream>>>(ru_param, c_param, Wt1, Wt2);

  const int gBuild = Nn * WROWU / 256;
  const int gProp = (Nn / 4) * 8;   // 4 rows/block (1 per wave) x 8 XCD slices

  // ===== conv1 diffusion (rows of 384 uint2, slices of 48 uint2 = 384 B) =====
  build_x0_ru<<<gBuild, 256, 0, stream>>>(x, h, A0);
  prop_dual_s<384, 48><<<gProp, 256, 0, stream>>>(
      (const uint2*)A0, (uint2*)T1f, (uint2*)T1b, rp_f, cwf, rp_b, cwb);
  prop_ck_s<384, 48><<<gProp, 256, 0, stream>>>(
      (const uint2*)T1f, (uint2*)T2f, rp_f, cwf, 2.f);
  prop_ck_s<384, 48><<<gProp, 256, 0, stream>>>(
      (const uint2*)T1b, (uint2*)T2b, rp_b, cwb, 2.f);

  // ===== conv1 projection: one MFMA GEMM K=480, fused sigmoid + r*h + u-store =====
  Msrc g1;
  g1.xs[0] = (const uint4*)A0;  g1.rh[0] = nullptr;
  g1.xs[1] = (const uint4*)T1f; g1.rh[1] = nullptr;
  g1.xs[2] = (const uint4*)T1b; g1.rh[2] = nullptr;
  g1.xs[3] = (const uint4*)T2f; g1.rh[3] = nullptr;
  g1.xs[4] = (const uint4*)T2b; g1.rh[4] = nullptr;
  gemm_mfma<128, 0><<<MROWS / 128, 256, 0, stream>>>(
      g1, 5, 0, Wt1, ru_bias, nullptr,
      (unsigned short*)rh0, (unsigned short*)Ubuf, nullptr, h);

  // ===== conv2 diffusion on rh (rows of 256 uint2, slices of 32 uint2 = 256 B) =====
  prop_dual_s<256, 32><<<gProp, 256, 0, stream>>>(
      (const uint2*)rh0, (uint2*)rh1f, (uint2*)rh1b, rp_f, cwf, rp_b, cwb);

  // conv2 pass A: terms 0,1,2 (weight base t0=0)
  Msrc g2a;
  g2a.xs[0] = (const uint4*)A0;  g2a.rh[0] = (const uint4*)rh0;
  g2a.xs[1] = (const uint4*)T1f; g2a.rh[1] = (const uint4*)rh1f;
  g2a.xs[2] = (const uint4*)T1b; g2a.rh[2] = (const uint4*)rh1b;
  g2a.xs[3] = nullptr; g2a.rh[3] = nullptr;
  g2a.xs[4] = nullptr; g2a.rh[4] = nullptr;
  gemm_mfma<64, 1><<<MROWS / 128, 256, 0, stream>>>(
      g2a, 3, 0, Wt2, c_bias, outp, nullptr, nullptr, nullptr, nullptr);

  // rh second-order terms (reuse rh0/rh1f storage after pass A consumed them)
  prop_ck_s<256, 32><<<gProp, 256, 0, stream>>>(
      (const uint2*)rh1f, (uint2*)rh0, rp_f, cwf, 2.f);   // rh2f
  prop_ck_s<256, 32><<<gProp, 256, 0, stream>>>(
      (const uint2*)rh1b, (uint2*)rh1f, rp_b, cwb, 2.f);  // rh2b

  // conv2 pass B: terms 3,4 (weight base t0=3) + fused GRU final
  Msrc g2b;
  g2b.xs[0] = (const uint4*)T2f; g2b.rh[0] = (const uint4*)rh0;
  g2b.xs[1] = (const uint4*)T2b; g2b.rh[1] = (const uint4*)rh1f;
  g2b.xs[2] = nullptr; g2b.rh[2] = nullptr;
  g2b.xs[3] = nullptr; g2b.rh[3] = nullptr;
  g2b.xs[4] = nullptr; g2b.rh[4] = nullptr;
  gemm_mfma<64, 2><<<MROWS / 128, 256, 0, stream>>>(
      g2b, 2, 3, Wt2, c_bias, outp, nullptr, nullptr,
      (const unsigned short*)Ubuf, h);
}